// Round 11
// baseline (698.215 us; speedup 1.0000x reference)
//
#include <hip/hip_runtime.h>
#include <math.h>

#define N_NODES 40000
#define N_EDGES 320000
#define F_IN 128
#define NHEAD 4
#define HC 256
#define NOUT 64
#define SLOTCAP 40   // max degree capacity; P(Poisson(8) >= 40) ~ 1e-18 per node

typedef __attribute__((ext_vector_type(8))) __bf16 bf16x8;
typedef __attribute__((ext_vector_type(4))) float f32x4;

static __device__ __forceinline__ unsigned short f2bf(float f) {
    union { float f; unsigned u; } v; v.f = f;
    unsigned r = v.u + 0x7FFFu + ((v.u >> 16) & 1u);
    return (unsigned short)(r >> 16);
}
static __device__ __forceinline__ float bf2f(unsigned short s) {
    union { unsigned u; float f; } v; v.u = ((unsigned)s) << 16;
    return v.f;
}

// ---------------- prep: weight converts + zero cursor/ticket/bnacc --------
__global__ __launch_bounds__(256) void prep_kernel(const float* __restrict__ W1,
                                                   const float* __restrict__ W2,
                                                   const float* __restrict__ linW,
                                                   unsigned short* __restrict__ W1t,
                                                   unsigned short* __restrict__ W2t,
                                                   unsigned short* __restrict__ linWt,
                                                   int* __restrict__ zero_ints,
                                                   float* __restrict__ bnacc) {
    int b = blockIdx.x, tid = threadIdx.x;
    if (b < 128) {
        int t = b * 256 + tid;
        int k = t >> 8, n = t & 255;
        W1t[n * 128 + k] = f2bf(W1[t]);
    } else if (b < 384) {
        int t = (b - 128) * 256 + tid;
        int k = t >> 8, n = t & 255;
        W2t[n * 256 + k] = f2bf(W2[t]);
    } else if (b < 448) {
        int t = (b - 384) * 256 + tid;
        int k = t >> 6, n = t & 63;
        linWt[n * 256 + k] = f2bf(linW[t]);
    } else if (b < 488) {
        int i = (b - 448) * 1024 + tid * 4;
        if (i < 40004) *(int4*)(zero_ints + i) = make_int4(0, 0, 0, 0);
    } else {
        if (tid < 512) bnacc[tid] = 0.f;
    }
}

// ---------------- wide MFMA GEMM: 64 rows x 256 cols, pipelined staging ----
// AMODE 1: A = f32[M,K] (convert in staging)
// AMODE 3: A = bf16[M,K], elu(x*sc+shift) in staging (via __expf), write h1p
// SCATTER 1: blocks >= 625 instead do direct-slot CSR scatter
template <int AMODE, int SCATTER>
__global__ __launch_bounds__(256) void gemm_wide(const void* __restrict__ Aptr,
                                                 const unsigned short* __restrict__ Bt,
                                                 const float* __restrict__ sc,
                                                 unsigned short* __restrict__ h1p,
                                                 unsigned short* __restrict__ Cb,
                                                 const float* __restrict__ asrc,
                                                 const float* __restrict__ adst,
                                                 float* __restrict__ es,
                                                 float* __restrict__ ed,
                                                 int K,
                                                 const int* __restrict__ ei,
                                                 int* __restrict__ cursor,
                                                 int* __restrict__ esorted) {
    __shared__ unsigned short As[64 * 32];
    __shared__ unsigned short Bs[256 * 32];
    int tid = threadIdx.x;
    if (SCATTER && blockIdx.x >= N_NODES / 64) {
        int e = (blockIdx.x - N_NODES / 64) * 256 + tid;
        if (e < N_EDGES) {
            int d = ei[N_EDGES + e];
            int s = ei[e];
            int pos = atomicAdd(&cursor[d], 1);
            esorted[d * SLOTCAP + pos] = s;
        }
        return;
    }
    int row0 = blockIdx.x * 64;
    int w = tid >> 6, lane = tid & 63;
    int quad = lane >> 4, l16 = lane & 15;
    f32x4 acc[4][4];
#pragma unroll
    for (int mi = 0; mi < 4; ++mi)
#pragma unroll
        for (int ni = 0; ni < 4; ++ni) acc[mi][ni] = (f32x4){0.f, 0.f, 0.f, 0.f};

    int srow = tid >> 2, schunk = (tid & 3) * 8;
    int brow = tid >> 1, bchunk = (tid & 1) * 16;

    float4 pa0, pa1;
    int4 pai;
    int4 pb[4];
    if (AMODE == 1) {
        const float* Af = (const float*)Aptr;
        size_t base = (size_t)(row0 + srow) * K + schunk;
        pa0 = *(const float4*)(Af + base);
        pa1 = *(const float4*)(Af + base + 4);
    } else {
        pai = *(const int4*)((const unsigned short*)Aptr + (size_t)(row0 + srow) * K + schunk);
    }
    {
        const unsigned short* s0 = Bt + (size_t)brow * K + bchunk;
        const unsigned short* s1 = Bt + (size_t)(128 + brow) * K + bchunk;
        pb[0] = *(const int4*)s0; pb[1] = *(const int4*)(s0 + 8);
        pb[2] = *(const int4*)s1; pb[3] = *(const int4*)(s1 + 8);
    }

    for (int kc = 0; kc < K; kc += 32) {
        union { int4 v; unsigned short u[8]; } aS;
        if (AMODE == 1) {
            aS.u[0] = f2bf(pa0.x); aS.u[1] = f2bf(pa0.y);
            aS.u[2] = f2bf(pa0.z); aS.u[3] = f2bf(pa0.w);
            aS.u[4] = f2bf(pa1.x); aS.u[5] = f2bf(pa1.y);
            aS.u[6] = f2bf(pa1.z); aS.u[7] = f2bf(pa1.w);
        } else {
            union { int4 v; unsigned short u[8]; } a;
            a.v = pai;
#pragma unroll
            for (int j = 0; j < 8; ++j) {
                int c = kc + schunk + j;
                float v = bf2f(a.u[j]) * sc[c] + sc[HC + c];
                v = v > 0.f ? v : (__expf(v) - 1.f);
                aS.u[j] = f2bf(v);
            }
        }
        int4 bS0 = pb[0], bS1 = pb[1], bS2 = pb[2], bS3 = pb[3];
        int kn = kc + 32;
        if (kn < K) {
            if (AMODE == 1) {
                const float* Af = (const float*)Aptr;
                size_t base = (size_t)(row0 + srow) * K + kn + schunk;
                pa0 = *(const float4*)(Af + base);
                pa1 = *(const float4*)(Af + base + 4);
            } else {
                pai = *(const int4*)((const unsigned short*)Aptr +
                                     (size_t)(row0 + srow) * K + kn + schunk);
            }
            const unsigned short* s0 = Bt + (size_t)brow * K + kn + bchunk;
            const unsigned short* s1 = Bt + (size_t)(128 + brow) * K + kn + bchunk;
            pb[0] = *(const int4*)s0; pb[1] = *(const int4*)(s0 + 8);
            pb[2] = *(const int4*)s1; pb[3] = *(const int4*)(s1 + 8);
        }
        *(int4*)(&As[srow * 32 + schunk]) = aS.v;
        if (AMODE == 3)
            *(int4*)(h1p + (size_t)(row0 + srow) * HC + kc + schunk) = aS.v;
        *(int4*)(&Bs[brow * 32 + bchunk]) = bS0;
        *(int4*)(&Bs[brow * 32 + bchunk + 8]) = bS1;
        *(int4*)(&Bs[(128 + brow) * 32 + bchunk]) = bS2;
        *(int4*)(&Bs[(128 + brow) * 32 + bchunk + 8]) = bS3;
        __syncthreads();
        bf16x8 af[4], bfr[4];
#pragma unroll
        for (int mi = 0; mi < 4; ++mi)
            af[mi] = *(const bf16x8*)(&As[(mi * 16 + l16) * 32 + quad * 8]);
#pragma unroll
        for (int ni = 0; ni < 4; ++ni)
            bfr[ni] = *(const bf16x8*)(&Bs[(w * 64 + ni * 16 + l16) * 32 + quad * 8]);
#pragma unroll
        for (int mi = 0; mi < 4; ++mi)
#pragma unroll
            for (int ni = 0; ni < 4; ++ni)
                acc[mi][ni] = __builtin_amdgcn_mfma_f32_16x16x32_bf16(
                    af[mi], bfr[ni], acc[mi][ni], 0, 0, 0);
        __syncthreads();
    }
#pragma unroll
    for (int mi = 0; mi < 4; ++mi)
#pragma unroll
        for (int ni = 0; ni < 4; ++ni) {
            int r0 = row0 + mi * 16 + quad * 4;
            int c = w * 64 + ni * 16 + l16;
#pragma unroll
            for (int r = 0; r < 4; ++r)
                Cb[(size_t)(r0 + r) * HC + c] = f2bf(acc[mi][ni][r]);
        }
    // fused attention scores (head = w), wave-local
    float as_v[4], ad_v[4];
#pragma unroll
    for (int ni = 0; ni < 4; ++ni) {
        int cl = ni * 16 + l16;
        as_v[ni] = asrc[w * 64 + cl];
        ad_v[ni] = adst[w * 64 + cl];
    }
#pragma unroll
    for (int mi = 0; mi < 4; ++mi)
#pragma unroll
        for (int r = 0; r < 4; ++r) {
            float s = 0.f, d = 0.f;
#pragma unroll
            for (int ni = 0; ni < 4; ++ni) {
                s += acc[mi][ni][r] * as_v[ni];
                d += acc[mi][ni][r] * ad_v[ni];
            }
#pragma unroll
            for (int off = 1; off < 16; off <<= 1) {
                s += __shfl_xor(s, off);
                d += __shfl_xor(d, off);
            }
            if (l16 == 0) {
                int row = row0 + mi * 16 + quad * 4 + r;
                es[(size_t)row * NHEAD + w] = s;
                ed[(size_t)row * NHEAD + w] = d;
            }
        }
}

// ---------------- final GEMM: out = jk @ linWt + b (plain, pipelined) -----
__global__ __launch_bounds__(256) void final_gemm(const unsigned short* __restrict__ A,
                                                  const unsigned short* __restrict__ Bt,
                                                  const float* __restrict__ bias,
                                                  float* __restrict__ Cf) {
    __shared__ unsigned short As[64 * 32];
    __shared__ unsigned short Bs[64 * 32];
    int tid = threadIdx.x;
    int row0 = blockIdx.x * 64;
    int wave = tid >> 6, lane = tid & 63;
    int wm = wave >> 1, wn = wave & 1;
    int quad = lane >> 4, l16 = lane & 15;
    f32x4 acc[2][2];
#pragma unroll
    for (int mi = 0; mi < 2; ++mi)
#pragma unroll
        for (int ni = 0; ni < 2; ++ni) acc[mi][ni] = (f32x4){0.f, 0.f, 0.f, 0.f};

    int srow = tid >> 2, schunk = (tid & 3) * 8;
    int4 pa = *(const int4*)(A + (size_t)(row0 + srow) * HC + schunk);
    int4 pbv = *(const int4*)(Bt + (size_t)srow * HC + schunk);

    for (int kc = 0; kc < HC; kc += 32) {
        int4 aS = pa, bS = pbv;
        int kn = kc + 32;
        if (kn < HC) {
            pa = *(const int4*)(A + (size_t)(row0 + srow) * HC + kn + schunk);
            pbv = *(const int4*)(Bt + (size_t)srow * HC + kn + schunk);
        }
        *(int4*)(&As[srow * 32 + schunk]) = aS;
        *(int4*)(&Bs[srow * 32 + schunk]) = bS;
        __syncthreads();
        bf16x8 af[2], bfr[2];
#pragma unroll
        for (int mi = 0; mi < 2; ++mi)
            af[mi] = *(const bf16x8*)(&As[(wm * 32 + mi * 16 + l16) * 32 + quad * 8]);
#pragma unroll
        for (int ni = 0; ni < 2; ++ni)
            bfr[ni] = *(const bf16x8*)(&Bs[(wn * 32 + ni * 16 + l16) * 32 + quad * 8]);
#pragma unroll
        for (int mi = 0; mi < 2; ++mi)
#pragma unroll
            for (int ni = 0; ni < 2; ++ni)
                acc[mi][ni] = __builtin_amdgcn_mfma_f32_16x16x32_bf16(
                    af[mi], bfr[ni], acc[mi][ni], 0, 0, 0);
        __syncthreads();
    }
#pragma unroll
    for (int mi = 0; mi < 2; ++mi)
#pragma unroll
        for (int ni = 0; ni < 2; ++ni) {
            int r0 = row0 + wm * 32 + mi * 16 + quad * 4;
            int c = wn * 32 + ni * 16 + l16;
#pragma unroll
            for (int r = 0; r < 4; ++r)
                Cf[(size_t)(r0 + r) * NOUT + c] = acc[mi][ni][r] + bias[c];
        }
}

// ------- softmax + aggregation: 2 nodes/wave, bf16 gather (16B/lane) ------
// JK=0: out = bf16(agg + bias). JK=1: out = bf16(max(h1p, agg + bias)).
// STATS=1: BN stats via NON-ATOMIC LDS transpose (disjoint ds_write per
//          thread) + 2 native global f32 atomics/thread + ticket finalize.
//          (R10's LDS float atomicAdd CAS-loop storm: 35->421 us. Never again.)
template <int JK, int STATS>
__global__ __launch_bounds__(256) void aggregate_kernel(const unsigned short* __restrict__ h,
                                                        const float* __restrict__ es,
                                                        const float* __restrict__ ed,
                                                        const int* __restrict__ deg,
                                                        const int* __restrict__ esorted,
                                                        const float* __restrict__ bias,
                                                        const unsigned short* __restrict__ h1p,
                                                        unsigned short* __restrict__ outb,
                                                        float* __restrict__ acc_g,
                                                        const float* __restrict__ gamma,
                                                        const float* __restrict__ beta,
                                                        float* __restrict__ sc,
                                                        int* __restrict__ ticket) {
    __shared__ float lsum[STATS ? 8 * HC : 1];   // [p][c], disjoint writes
    __shared__ float lsq[STATS ? 8 * HC : 1];
    int tid = threadIdx.x;
    int wave = tid >> 6, lane = tid & 63;
    int half = lane >> 5, l = lane & 31;       // 2 nodes per wave, 32 lanes each
    int node = blockIdx.x * 8 + wave * 2 + half;
    int p = wave * 2 + half;                   // node slot within block (0..7)
    int hh = l >> 3;                            // 8 channels/lane -> head = l>>3
    float edv = ed[node * NHEAD + hh];
    int d = deg[node];
    int beg = node * SLOTCAP;
    float dsum = 0.f;
    float a[8] = {0.f, 0.f, 0.f, 0.f, 0.f, 0.f, 0.f, 0.f};
    for (int i = 0; i < d; i += 8) {
        int s[8];
        int4 hv[8];
        float ep[8];
#pragma unroll
        for (int j = 0; j < 8; ++j) {
            int slot = i + j;
            s[j] = esorted[beg + (slot < d ? slot : d - 1)];
        }
#pragma unroll
        for (int j = 0; j < 8; ++j)
            hv[j] = *(const int4*)(h + (size_t)s[j] * HC + l * 8);
#pragma unroll
        for (int j = 0; j < 8; ++j)
            ep[j] = es[s[j] * NHEAD + hh];
#pragma unroll
        for (int j = 0; j < 8; ++j) {
            float e = ep[j] + edv;
            e = e > 0.f ? e : 0.2f * e;
            float w = __expf(e);
            w = (i + j < d) ? w : 0.f;   // adding exact 0.0f: order-identical sums
            dsum += w;
            union { int4 v; unsigned short u[8]; } hu;
            hu.v = hv[j];
#pragma unroll
            for (int k = 0; k < 8; ++k) a[k] += w * bf2f(hu.u[k]);
        }
    }
    float inv = 1.f / (dsum + 1e-16f);
    float4 bv0 = *(const float4*)(bias + l * 8);
    float4 bv1 = *(const float4*)(bias + l * 8 + 4);
    float bb[8] = {bv0.x, bv0.y, bv0.z, bv0.w, bv1.x, bv1.y, bv1.z, bv1.w};
    union { int4 v; unsigned short u[8]; } o;
    if (JK == 0) {
#pragma unroll
        for (int k = 0; k < 8; ++k) {
            float v = a[k] * inv + bb[k];
            o.u[k] = f2bf(v);
            if (STATS) {
                lsum[p * HC + l * 8 + k] = v;       // plain ds_write, disjoint
                lsq[p * HC + l * 8 + k] = v * v;
            }
        }
    } else {
        union { int4 v; unsigned short u[8]; } h1u;
        h1u.v = *(const int4*)(h1p + (size_t)node * HC + l * 8);
#pragma unroll
        for (int k = 0; k < 8; ++k)
            o.u[k] = f2bf(fmaxf(bf2f(h1u.u[k]), a[k] * inv + bb[k]));
    }
    *(int4*)(outb + (size_t)node * HC + l * 8) = o.v;

    if (STATS) {
        __syncthreads();
        // thread tid reduces channel tid across the block's 8 nodes
        float s = 0.f, q = 0.f;
#pragma unroll
        for (int pp = 0; pp < 8; ++pp) {
            s += lsum[pp * HC + tid];
            q += lsq[pp * HC + tid];
        }
        atomicAdd(&acc_g[tid], s);          // native global f32 atomic
        atomicAdd(&acc_g[HC + tid], q);
        __threadfence();
        __syncthreads();
        __shared__ int is_last;
        if (tid == 0) is_last = (atomicAdd(ticket, 1) == (int)gridDim.x - 1);
        __syncthreads();
        if (is_last) {
            float sum = atomicAdd(&acc_g[tid], 0.f);   // coherent readback
            float sq  = atomicAdd(&acc_g[HC + tid], 0.f);
            float mean = sum * (1.f / N_NODES);
            float var = sq * (1.f / N_NODES) - mean * mean;
            float rinv = rsqrtf(var + 1e-5f);
            float scale = gamma[tid] * rinv;
            sc[tid] = scale;
            sc[HC + tid] = beta[tid] - mean * scale;
        }
    }
}

extern "C" void kernel_launch(void* const* d_in, const int* in_sizes, int n_in,
                              void* d_out, int out_size, void* d_ws, size_t ws_size,
                              hipStream_t stream) {
    const float* x      = (const float*)d_in[0];
    const int*   ei     = (const int*)d_in[1];
    const float* W1     = (const float*)d_in[2];
    const float* a1_src = (const float*)d_in[3];
    const float* a1_dst = (const float*)d_in[4];
    const float* b1     = (const float*)d_in[5];
    const float* bn_g   = (const float*)d_in[6];
    const float* bn_b   = (const float*)d_in[7];
    const float* W2     = (const float*)d_in[8];
    const float* a2_src = (const float*)d_in[9];
    const float* a2_dst = (const float*)d_in[10];
    const float* b2     = (const float*)d_in[11];
    const float* linW   = (const float*)d_in[12];
    const float* linb   = (const float*)d_in[13];
    float* out = (float*)d_out;

    char* ws = (char*)d_ws;
    const size_t NHC_BF = (size_t)N_NODES * HC * 2;   // 20.48 MB
    unsigned short* hpre_b  = (unsigned short*)(ws);                  // h_pre (both layers)
    unsigned short* h1agg_b = (unsigned short*)(ws + NHC_BF);         // agg1 (pre-BN)
    unsigned short* h1p_b   = (unsigned short*)(ws + 2 * NHC_BF);     // elu(bn(h1))
    unsigned short* jk_b    = (unsigned short*)(ws + 3 * NHC_BF);     // max(h1p, h2)
    char* p = ws + 4 * NHC_BF;
    unsigned short* W1t   = (unsigned short*)p; p += (size_t)F_IN * HC * 2;
    unsigned short* W2t   = (unsigned short*)p; p += (size_t)HC * HC * 2;
    unsigned short* linWt = (unsigned short*)p; p += (size_t)HC * NOUT * 2;
    float* e_src   = (float*)p;  p += (size_t)N_NODES * NHEAD * 4;
    float* e_dst   = (float*)p;  p += (size_t)N_NODES * NHEAD * 4;
    // zero region: cursor + ticket (40004 ints)
    int*   cursor  = (int*)p;    p += (size_t)N_NODES * 4;
    int*   ticket  = (int*)p;    p += 4 * 4;
    int*   esorted = (int*)p;    p += (size_t)N_NODES * SLOTCAP * 4;  // 6.4 MB
    float* bnacc   = (float*)p;  p += 2 * HC * 4;
    float* bnsc    = (float*)p;  p += 2 * HC * 4;

    // 1. prep: weight converts + zero cursor/ticket/bnacc
    prep_kernel<<<489, 256, 0, stream>>>(W1, W2, linW, W1t, W2t, linWt, cursor, bnacc);

    // 2. layer-1 wide GEMM (f32 A) + fused scores + fused CSR scatter
    gemm_wide<1, 1><<<N_NODES / 64 + (N_EDGES + 255) / 256, 256, 0, stream>>>(
        x, W1t, nullptr, nullptr, hpre_b, a1_src, a1_dst, e_src, e_dst, F_IN,
        ei, cursor, esorted);

    // 3. aggregate 1 + fused BN stats (non-atomic LDS) + ticket finalize
    aggregate_kernel<0, 1><<<N_NODES / 8, 256, 0, stream>>>(
        hpre_b, e_src, e_dst, cursor, esorted, b1, nullptr, h1agg_b,
        bnacc, bn_g, bn_b, bnsc, ticket);

    // 4. layer-2 wide GEMM (BN+ELU fused into staging, h1p written) + scores
    gemm_wide<3, 0><<<N_NODES / 64, 256, 0, stream>>>(
        h1agg_b, W2t, bnsc, h1p_b, hpre_b, a2_src, a2_dst, e_src, e_dst, HC,
        nullptr, nullptr, nullptr);

    // 5. aggregate 2 + JK max
    aggregate_kernel<1, 0><<<N_NODES / 8, 256, 0, stream>>>(
        hpre_b, e_src, e_dst, cursor, esorted, b2, h1p_b, jk_b,
        nullptr, nullptr, nullptr, nullptr, nullptr);

    // 6. final: plain GEMM jk @ linWt + b
    final_gemm<<<N_NODES / 64, 256, 0, stream>>>(jk_b, linWt, linb, out);
}

// Round 12
// 232.294 us; speedup vs baseline: 3.0057x; 3.0057x over previous
//
#include <hip/hip_runtime.h>
#include <math.h>

#define N_NODES 40000
#define N_EDGES 320000
#define F_IN 128
#define NHEAD 4
#define HC 256
#define NOUT 64
#define SLOTCAP 40   // max degree capacity; P(Poisson(8) >= 40) ~ 1e-18 per node

typedef __attribute__((ext_vector_type(8))) __bf16 bf16x8;
typedef __attribute__((ext_vector_type(4))) float f32x4;

static __device__ __forceinline__ unsigned short f2bf(float f) {
    union { float f; unsigned u; } v; v.f = f;
    unsigned r = v.u + 0x7FFFu + ((v.u >> 16) & 1u);
    return (unsigned short)(r >> 16);
}
static __device__ __forceinline__ float bf2f(unsigned short s) {
    union { unsigned u; float f; } v; v.u = ((unsigned)s) << 16;
    return v.f;
}

// ---------------- prep: weight converts + zero cursor/ticket/bnacc --------
__global__ __launch_bounds__(256) void prep_kernel(const float* __restrict__ W1,
                                                   const float* __restrict__ W2,
                                                   const float* __restrict__ linW,
                                                   unsigned short* __restrict__ W1t,
                                                   unsigned short* __restrict__ W2t,
                                                   unsigned short* __restrict__ linWt,
                                                   int* __restrict__ zero_ints,
                                                   float* __restrict__ bnacc) {
    int b = blockIdx.x, tid = threadIdx.x;
    if (b < 128) {
        int t = b * 256 + tid;
        int k = t >> 8, n = t & 255;
        W1t[n * 128 + k] = f2bf(W1[t]);
    } else if (b < 384) {
        int t = (b - 128) * 256 + tid;
        int k = t >> 8, n = t & 255;
        W2t[n * 256 + k] = f2bf(W2[t]);
    } else if (b < 448) {
        int t = (b - 384) * 256 + tid;
        int k = t >> 6, n = t & 63;
        linWt[n * 256 + k] = f2bf(linW[t]);
    } else if (b < 488) {
        int i = (b - 448) * 1024 + tid * 4;
        if (i < 40004) *(int4*)(zero_ints + i) = make_int4(0, 0, 0, 0);
    } else {
        if (tid < 512) bnacc[tid] = 0.f;
    }
}

// ---------------- wide MFMA GEMM: 64 rows x 256 cols, pipelined staging ----
// AMODE 1: A = f32[M,K] (convert in staging)
// AMODE 3: A = bf16[M,K], elu(x*sc+shift) in staging (via __expf), write h1p
// SCATTER 1: blocks >= 625 instead do direct-slot CSR scatter
template <int AMODE, int SCATTER>
__global__ __launch_bounds__(256) void gemm_wide(const void* __restrict__ Aptr,
                                                 const unsigned short* __restrict__ Bt,
                                                 const float* __restrict__ sc,
                                                 unsigned short* __restrict__ h1p,
                                                 unsigned short* __restrict__ Cb,
                                                 const float* __restrict__ asrc,
                                                 const float* __restrict__ adst,
                                                 float* __restrict__ es,
                                                 float* __restrict__ ed,
                                                 int K,
                                                 const int* __restrict__ ei,
                                                 int* __restrict__ cursor,
                                                 int* __restrict__ esorted) {
    __shared__ unsigned short As[64 * 32];
    __shared__ unsigned short Bs[256 * 32];
    int tid = threadIdx.x;
    if (SCATTER && blockIdx.x >= N_NODES / 64) {
        int e = (blockIdx.x - N_NODES / 64) * 256 + tid;
        if (e < N_EDGES) {
            int d = ei[N_EDGES + e];
            int s = ei[e];
            int pos = atomicAdd(&cursor[d], 1);
            esorted[d * SLOTCAP + pos] = s;
        }
        return;
    }
    int row0 = blockIdx.x * 64;
    int w = tid >> 6, lane = tid & 63;
    int quad = lane >> 4, l16 = lane & 15;
    f32x4 acc[4][4];
#pragma unroll
    for (int mi = 0; mi < 4; ++mi)
#pragma unroll
        for (int ni = 0; ni < 4; ++ni) acc[mi][ni] = (f32x4){0.f, 0.f, 0.f, 0.f};

    int srow = tid >> 2, schunk = (tid & 3) * 8;
    int brow = tid >> 1, bchunk = (tid & 1) * 16;

    float4 pa0, pa1;
    int4 pai;
    int4 pb[4];
    if (AMODE == 1) {
        const float* Af = (const float*)Aptr;
        size_t base = (size_t)(row0 + srow) * K + schunk;
        pa0 = *(const float4*)(Af + base);
        pa1 = *(const float4*)(Af + base + 4);
    } else {
        pai = *(const int4*)((const unsigned short*)Aptr + (size_t)(row0 + srow) * K + schunk);
    }
    {
        const unsigned short* s0 = Bt + (size_t)brow * K + bchunk;
        const unsigned short* s1 = Bt + (size_t)(128 + brow) * K + bchunk;
        pb[0] = *(const int4*)s0; pb[1] = *(const int4*)(s0 + 8);
        pb[2] = *(const int4*)s1; pb[3] = *(const int4*)(s1 + 8);
    }

    for (int kc = 0; kc < K; kc += 32) {
        union { int4 v; unsigned short u[8]; } aS;
        if (AMODE == 1) {
            aS.u[0] = f2bf(pa0.x); aS.u[1] = f2bf(pa0.y);
            aS.u[2] = f2bf(pa0.z); aS.u[3] = f2bf(pa0.w);
            aS.u[4] = f2bf(pa1.x); aS.u[5] = f2bf(pa1.y);
            aS.u[6] = f2bf(pa1.z); aS.u[7] = f2bf(pa1.w);
        } else {
            union { int4 v; unsigned short u[8]; } a;
            a.v = pai;
#pragma unroll
            for (int j = 0; j < 8; ++j) {
                int c = kc + schunk + j;
                float v = bf2f(a.u[j]) * sc[c] + sc[HC + c];
                v = v > 0.f ? v : (__expf(v) - 1.f);
                aS.u[j] = f2bf(v);
            }
        }
        int4 bS0 = pb[0], bS1 = pb[1], bS2 = pb[2], bS3 = pb[3];
        int kn = kc + 32;
        if (kn < K) {
            if (AMODE == 1) {
                const float* Af = (const float*)Aptr;
                size_t base = (size_t)(row0 + srow) * K + kn + schunk;
                pa0 = *(const float4*)(Af + base);
                pa1 = *(const float4*)(Af + base + 4);
            } else {
                pai = *(const int4*)((const unsigned short*)Aptr +
                                     (size_t)(row0 + srow) * K + kn + schunk);
            }
            const unsigned short* s0 = Bt + (size_t)brow * K + kn + bchunk;
            const unsigned short* s1 = Bt + (size_t)(128 + brow) * K + kn + bchunk;
            pb[0] = *(const int4*)s0; pb[1] = *(const int4*)(s0 + 8);
            pb[2] = *(const int4*)s1; pb[3] = *(const int4*)(s1 + 8);
        }
        *(int4*)(&As[srow * 32 + schunk]) = aS.v;
        if (AMODE == 3)
            *(int4*)(h1p + (size_t)(row0 + srow) * HC + kc + schunk) = aS.v;
        *(int4*)(&Bs[brow * 32 + bchunk]) = bS0;
        *(int4*)(&Bs[brow * 32 + bchunk + 8]) = bS1;
        *(int4*)(&Bs[(128 + brow) * 32 + bchunk]) = bS2;
        *(int4*)(&Bs[(128 + brow) * 32 + bchunk + 8]) = bS3;
        __syncthreads();
        bf16x8 af[4], bfr[4];
#pragma unroll
        for (int mi = 0; mi < 4; ++mi)
            af[mi] = *(const bf16x8*)(&As[(mi * 16 + l16) * 32 + quad * 8]);
#pragma unroll
        for (int ni = 0; ni < 4; ++ni)
            bfr[ni] = *(const bf16x8*)(&Bs[(w * 64 + ni * 16 + l16) * 32 + quad * 8]);
#pragma unroll
        for (int mi = 0; mi < 4; ++mi)
#pragma unroll
            for (int ni = 0; ni < 4; ++ni)
                acc[mi][ni] = __builtin_amdgcn_mfma_f32_16x16x32_bf16(
                    af[mi], bfr[ni], acc[mi][ni], 0, 0, 0);
        __syncthreads();
    }
#pragma unroll
    for (int mi = 0; mi < 4; ++mi)
#pragma unroll
        for (int ni = 0; ni < 4; ++ni) {
            int r0 = row0 + mi * 16 + quad * 4;
            int c = w * 64 + ni * 16 + l16;
#pragma unroll
            for (int r = 0; r < 4; ++r)
                Cb[(size_t)(r0 + r) * HC + c] = f2bf(acc[mi][ni][r]);
        }
    // fused attention scores (head = w), wave-local
    float as_v[4], ad_v[4];
#pragma unroll
    for (int ni = 0; ni < 4; ++ni) {
        int cl = ni * 16 + l16;
        as_v[ni] = asrc[w * 64 + cl];
        ad_v[ni] = adst[w * 64 + cl];
    }
#pragma unroll
    for (int mi = 0; mi < 4; ++mi)
#pragma unroll
        for (int r = 0; r < 4; ++r) {
            float s = 0.f, d = 0.f;
#pragma unroll
            for (int ni = 0; ni < 4; ++ni) {
                s += acc[mi][ni][r] * as_v[ni];
                d += acc[mi][ni][r] * ad_v[ni];
            }
#pragma unroll
            for (int off = 1; off < 16; off <<= 1) {
                s += __shfl_xor(s, off);
                d += __shfl_xor(d, off);
            }
            if (l16 == 0) {
                int row = row0 + mi * 16 + quad * 4 + r;
                es[(size_t)row * NHEAD + w] = s;
                ed[(size_t)row * NHEAD + w] = d;
            }
        }
}

// ---------------- final GEMM: out = jk @ linWt + b (plain, pipelined) -----
__global__ __launch_bounds__(256) void final_gemm(const unsigned short* __restrict__ A,
                                                  const unsigned short* __restrict__ Bt,
                                                  const float* __restrict__ bias,
                                                  float* __restrict__ Cf) {
    __shared__ unsigned short As[64 * 32];
    __shared__ unsigned short Bs[64 * 32];
    int tid = threadIdx.x;
    int row0 = blockIdx.x * 64;
    int wave = tid >> 6, lane = tid & 63;
    int wm = wave >> 1, wn = wave & 1;
    int quad = lane >> 4, l16 = lane & 15;
    f32x4 acc[2][2];
#pragma unroll
    for (int mi = 0; mi < 2; ++mi)
#pragma unroll
        for (int ni = 0; ni < 2; ++ni) acc[mi][ni] = (f32x4){0.f, 0.f, 0.f, 0.f};

    int srow = tid >> 2, schunk = (tid & 3) * 8;
    int4 pa = *(const int4*)(A + (size_t)(row0 + srow) * HC + schunk);
    int4 pbv = *(const int4*)(Bt + (size_t)srow * HC + schunk);

    for (int kc = 0; kc < HC; kc += 32) {
        int4 aS = pa, bS = pbv;
        int kn = kc + 32;
        if (kn < HC) {
            pa = *(const int4*)(A + (size_t)(row0 + srow) * HC + kn + schunk);
            pbv = *(const int4*)(Bt + (size_t)srow * HC + kn + schunk);
        }
        *(int4*)(&As[srow * 32 + schunk]) = aS;
        *(int4*)(&Bs[srow * 32 + schunk]) = bS;
        __syncthreads();
        bf16x8 af[2], bfr[2];
#pragma unroll
        for (int mi = 0; mi < 2; ++mi)
            af[mi] = *(const bf16x8*)(&As[(wm * 32 + mi * 16 + l16) * 32 + quad * 8]);
#pragma unroll
        for (int ni = 0; ni < 2; ++ni)
            bfr[ni] = *(const bf16x8*)(&Bs[(wn * 32 + ni * 16 + l16) * 32 + quad * 8]);
#pragma unroll
        for (int mi = 0; mi < 2; ++mi)
#pragma unroll
            for (int ni = 0; ni < 2; ++ni)
                acc[mi][ni] = __builtin_amdgcn_mfma_f32_16x16x32_bf16(
                    af[mi], bfr[ni], acc[mi][ni], 0, 0, 0);
        __syncthreads();
    }
#pragma unroll
    for (int mi = 0; mi < 2; ++mi)
#pragma unroll
        for (int ni = 0; ni < 2; ++ni) {
            int r0 = row0 + wm * 32 + mi * 16 + quad * 4;
            int c = wn * 32 + ni * 16 + l16;
#pragma unroll
            for (int r = 0; r < 4; ++r)
                Cf[(size_t)(r0 + r) * NOUT + c] = acc[mi][ni][r] + bias[c];
        }
}

// ------- softmax + aggregation: 2 nodes/wave, bf16 gather (16B/lane) ------
// JK=0: out = bf16(agg + bias). JK=1: out = bf16(max(h1p, agg + bias)).
// NOTE: do NOT fuse BN stats here. R10 (LDS f32 atomics: CAS storm, 421us)
// and R11 (5000-block global atomics: 5000-way contention, 537us) both
// catastrophically regressed this kernel. Stats need a few-block kernel.
template <int JK>
__global__ __launch_bounds__(256) void aggregate_kernel(const unsigned short* __restrict__ h,
                                                        const float* __restrict__ es,
                                                        const float* __restrict__ ed,
                                                        const int* __restrict__ deg,
                                                        const int* __restrict__ esorted,
                                                        const float* __restrict__ bias,
                                                        const unsigned short* __restrict__ h1p,
                                                        unsigned short* __restrict__ outb) {
    int tid = threadIdx.x;
    int wave = tid >> 6, lane = tid & 63;
    int half = lane >> 5, l = lane & 31;       // 2 nodes per wave, 32 lanes each
    int node = blockIdx.x * 8 + wave * 2 + half;
    int hh = l >> 3;                            // 8 channels/lane -> head = l>>3
    float edv = ed[node * NHEAD + hh];
    int d = deg[node];
    int beg = node * SLOTCAP;
    float dsum = 0.f;
    float a[8] = {0.f, 0.f, 0.f, 0.f, 0.f, 0.f, 0.f, 0.f};
    for (int i = 0; i < d; i += 8) {
        int s[8];
        int4 hv[8];
        float ep[8];
#pragma unroll
        for (int j = 0; j < 8; ++j) {
            int slot = i + j;
            s[j] = esorted[beg + (slot < d ? slot : d - 1)];
        }
#pragma unroll
        for (int j = 0; j < 8; ++j)
            hv[j] = *(const int4*)(h + (size_t)s[j] * HC + l * 8);
#pragma unroll
        for (int j = 0; j < 8; ++j)
            ep[j] = es[s[j] * NHEAD + hh];
#pragma unroll
        for (int j = 0; j < 8; ++j) {
            float e = ep[j] + edv;
            e = e > 0.f ? e : 0.2f * e;
            float w = __expf(e);
            w = (i + j < d) ? w : 0.f;   // adding exact 0.0f: order-identical sums
            dsum += w;
            union { int4 v; unsigned short u[8]; } hu;
            hu.v = hv[j];
#pragma unroll
            for (int k = 0; k < 8; ++k) a[k] += w * bf2f(hu.u[k]);
        }
    }
    float inv = 1.f / (dsum + 1e-16f);
    float4 bv0 = *(const float4*)(bias + l * 8);
    float4 bv1 = *(const float4*)(bias + l * 8 + 4);
    float bb[8] = {bv0.x, bv0.y, bv0.z, bv0.w, bv1.x, bv1.y, bv1.z, bv1.w};
    union { int4 v; unsigned short u[8]; } o;
    if (JK == 0) {
#pragma unroll
        for (int k = 0; k < 8; ++k) o.u[k] = f2bf(a[k] * inv + bb[k]);
    } else {
        union { int4 v; unsigned short u[8]; } h1u;
        h1u.v = *(const int4*)(h1p + (size_t)node * HC + l * 8);
#pragma unroll
        for (int k = 0; k < 8; ++k)
            o.u[k] = f2bf(fmaxf(bf2f(h1u.u[k]), a[k] * inv + bb[k]));
    }
    *(int4*)(outb + (size_t)node * HC + l * 8) = o.v;
}

// ---------------- batch norm stats + fused last-block finalize -------------
// 200 blocks: ~102K global atomics total (100-way contention) — proven cheap.
__global__ __launch_bounds__(256) void bn_stats_kernel(const unsigned short* __restrict__ x,
                                                       float* __restrict__ acc,
                                                       const float* __restrict__ gamma,
                                                       const float* __restrict__ beta,
                                                       float* __restrict__ sc,
                                                       int* __restrict__ ticket) {
    int c = threadIdx.x;
    int r0 = blockIdx.x * 200;
    float s = 0.f, s2 = 0.f;
    for (int r = r0; r < r0 + 200; ++r) {
        float v = bf2f(x[(size_t)r * HC + c]);
        s += v; s2 += v * v;
    }
    atomicAdd(&acc[c], s);
    atomicAdd(&acc[HC + c], s2);
    __threadfence();
    __syncthreads();
    __shared__ int is_last;
    if (c == 0) is_last = (atomicAdd(ticket, 1) == (int)gridDim.x - 1);
    __syncthreads();
    if (is_last) {
        float sum = atomicAdd(&acc[c], 0.f);   // coherent readback
        float sq  = atomicAdd(&acc[HC + c], 0.f);
        float mean = sum * (1.f / N_NODES);
        float var = sq * (1.f / N_NODES) - mean * mean;
        float inv = rsqrtf(var + 1e-5f);
        float scale = gamma[c] * inv;
        sc[c] = scale;
        sc[HC + c] = beta[c] - mean * scale;
    }
}

extern "C" void kernel_launch(void* const* d_in, const int* in_sizes, int n_in,
                              void* d_out, int out_size, void* d_ws, size_t ws_size,
                              hipStream_t stream) {
    const float* x      = (const float*)d_in[0];
    const int*   ei     = (const int*)d_in[1];
    const float* W1     = (const float*)d_in[2];
    const float* a1_src = (const float*)d_in[3];
    const float* a1_dst = (const float*)d_in[4];
    const float* b1     = (const float*)d_in[5];
    const float* bn_g   = (const float*)d_in[6];
    const float* bn_b   = (const float*)d_in[7];
    const float* W2     = (const float*)d_in[8];
    const float* a2_src = (const float*)d_in[9];
    const float* a2_dst = (const float*)d_in[10];
    const float* b2     = (const float*)d_in[11];
    const float* linW   = (const float*)d_in[12];
    const float* linb   = (const float*)d_in[13];
    float* out = (float*)d_out;

    char* ws = (char*)d_ws;
    const size_t NHC_BF = (size_t)N_NODES * HC * 2;   // 20.48 MB
    unsigned short* hpre_b  = (unsigned short*)(ws);                  // h_pre (both layers)
    unsigned short* h1agg_b = (unsigned short*)(ws + NHC_BF);         // agg1 (pre-BN)
    unsigned short* h1p_b   = (unsigned short*)(ws + 2 * NHC_BF);     // elu(bn(h1))
    unsigned short* jk_b    = (unsigned short*)(ws + 3 * NHC_BF);     // max(h1p, h2)
    char* p = ws + 4 * NHC_BF;
    unsigned short* W1t   = (unsigned short*)p; p += (size_t)F_IN * HC * 2;
    unsigned short* W2t   = (unsigned short*)p; p += (size_t)HC * HC * 2;
    unsigned short* linWt = (unsigned short*)p; p += (size_t)HC * NOUT * 2;
    float* e_src   = (float*)p;  p += (size_t)N_NODES * NHEAD * 4;
    float* e_dst   = (float*)p;  p += (size_t)N_NODES * NHEAD * 4;
    // zero region: cursor + ticket (40004 ints)
    int*   cursor  = (int*)p;    p += (size_t)N_NODES * 4;
    int*   ticket  = (int*)p;    p += 4 * 4;
    int*   esorted = (int*)p;    p += (size_t)N_NODES * SLOTCAP * 4;  // 6.4 MB
    float* bnacc   = (float*)p;  p += 2 * HC * 4;
    float* bnsc    = (float*)p;  p += 2 * HC * 4;

    // 1. prep: weight converts + zero cursor/ticket/bnacc
    prep_kernel<<<489, 256, 0, stream>>>(W1, W2, linW, W1t, W2t, linWt, cursor, bnacc);

    // 2. layer-1 wide GEMM (f32 A) + fused scores + fused CSR scatter
    gemm_wide<1, 1><<<N_NODES / 64 + (N_EDGES + 255) / 256, 256, 0, stream>>>(
        x, W1t, nullptr, nullptr, hpre_b, a1_src, a1_dst, e_src, e_dst, F_IN,
        ei, cursor, esorted);

    // 3. aggregate 1
    aggregate_kernel<0><<<N_NODES / 8, 256, 0, stream>>>(
        hpre_b, e_src, e_dst, cursor, esorted, b1, nullptr, h1agg_b);

    // 4. BN stats + finalize (ticket-fused, 200 blocks)
    bn_stats_kernel<<<N_NODES / 200, 256, 0, stream>>>(h1agg_b, bnacc, bn_g, bn_b,
                                                       bnsc, ticket);

    // 5. layer-2 wide GEMM (BN+ELU fused into staging, h1p written) + scores
    gemm_wide<3, 0><<<N_NODES / 64, 256, 0, stream>>>(
        h1agg_b, W2t, bnsc, h1p_b, hpre_b, a2_src, a2_dst, e_src, e_dst, HC,
        nullptr, nullptr, nullptr);

    // 6. aggregate 2 + JK max
    aggregate_kernel<1><<<N_NODES / 8, 256, 0, stream>>>(
        hpre_b, e_src, e_dst, cursor, esorted, b2, h1p_b, jk_b);

    // 7. final: plain GEMM jk @ linWt + b
    final_gemm<<<N_NODES / 64, 256, 0, stream>>>(jk_b, linWt, linb, out);
}